// Round 5
// baseline (292.859 us; speedup 1.0000x reference)
//
#include <hip/hip_runtime.h>
#include <hip/hip_bf16.h>

// Problem: out[128,12288] = [ clip(x[:, :6144] @ R, 0, 1) | zeros ]
// M=128, K=N=6144. R streamed once (151 MB fp32).
// Theory: natural pitches (0x6000/0x3000) channel-camp the L2/MALL hash.
// All derived buffers padded to pitch 6208 elements (row shift 0x80/0x100);
// heavy R read is fully sequential (register transpose, no LDS);
// gemm reads padded RT rows in 512B chunks via global_load_lds.

#define NPIX 12288
#define NV   6144
#define MR   128
#define KST  128
#define LDK  6208   // RT row pitch (shorts)
#define LDA  6208   // A row pitch (shorts)
#define LDP  6208   // partial-slot row pitch (floats)
#define PARTF ((size_t)MR * LDP)

typedef __attribute__((ext_vector_type(8))) short bf16x8;
typedef __attribute__((ext_vector_type(4))) float f32x4;
typedef __attribute__((ext_vector_type(4))) unsigned u32x4;

__device__ __forceinline__ unsigned pk2(float lo, float hi) {
    __hip_bfloat162 h = __float22bfloat162_rn(make_float2(lo, hi));
    union { __hip_bfloat162 h; unsigned u; } v; v.h = h; return v.u;
}

__device__ __forceinline__ void gld16(const void* g, void* l) {
    __builtin_amdgcn_global_load_lds(
        (const __attribute__((address_space(1))) void*)g,
        (__attribute__((address_space(3))) void*)l, 16, 0, 0);
}

// ---- prep: x[:, :6144] fp32 -> bf16 A[128][LDA] ----
__global__ __launch_bounds__(256) void prep_kernel(const float* __restrict__ x,
                                                   unsigned short* __restrict__ abf) {
    int q = blockIdx.x * 256 + threadIdx.x;   // 0 .. 98303
    int m = q / (NV / 8);
    int r = q % (NV / 8);
    int k = r * 8;
    const float* src = x + (size_t)m * NPIX + k;
    f32x4 a = *(const f32x4*)(src);
    f32x4 b = *(const f32x4*)(src + 4);
    u32x4 o;
    o[0] = pk2(a[0], a[1]); o[1] = pk2(a[2], a[3]);
    o[2] = pk2(b[0], b[1]); o[3] = pk2(b[2], b[3]);
    *(u32x4*)(abf + (size_t)m * LDA + k) = o;
}

// ---- trans: R[k][n] fp32 -> RT[n][LDK] bf16. LDS-free register transpose.
// Wave reads 8 full-row 1KB spans (lane i: 16B at n0+4*lane), packs 8k x 4n
// in registers, stores 4 x 16B. Block = [32 k][256 n]; 4 waves cooperatively
// fill each 64B line of RT (k-span 32 shorts). Grid 192 x 24 = 4608.
__global__ __launch_bounds__(256) void trans_kernel(const float* __restrict__ R,
                                                    unsigned short* __restrict__ RT) {
    const int tid = threadIdx.x;
    const int w = tid >> 6, l = tid & 63;
    const int band = blockIdx.x % 192;        // k-band of 32 rows
    const int nc   = blockIdx.x / 192;        // n-chunk of 256 cols
    const int k0 = band * 32 + w * 8;         // this wave's 8 k-rows
    const int n0 = nc * 256 + l * 4;          // this lane's 4 n-cols
    const float* src = R + (size_t)k0 * NV + n0;
    f32x4 r[8];
    #pragma unroll
    for (int j = 0; j < 8; ++j) r[j] = *(const f32x4*)(src + (size_t)j * NV);
    #pragma unroll
    for (int c = 0; c < 4; ++c) {
        u32x4 o;
        o[0] = pk2(r[0][c], r[1][c]);
        o[1] = pk2(r[2][c], r[3][c]);
        o[2] = pk2(r[4][c], r[5][c]);
        o[3] = pk2(r[6][c], r[7][c]);
        *(u32x4*)(RT + (size_t)(n0 + c) * LDK + k0) = o;
    }
}

// ---- gemm2: A[128][LDA]bf16 x RT[n][LDK]bf16 -> 8 partial slots in ws ----
// grid 768 = 96 stripes x 8 k-chunks (chunk = bid&7 -> XCD-aligned).
// Per step: stage B-tile [64 n][128 k] bf16 (16KB) via 4x global_load_lds
// dwordx4/thread, source pre-swizzled; ds_read_b128 same swizzle; 32 MFMA/wave.
__global__ __launch_bounds__(256) void gemm2_kernel(
        const unsigned short* __restrict__ A,
        const unsigned short* __restrict__ RT,
        float* __restrict__ wpart) {
    __shared__ unsigned char Bs[2][16384];

    const int tid = threadIdx.x;
    const int w = tid >> 6, l = tid & 63;
    const int ln = l & 15, lg = l >> 4;
    const int chunk = blockIdx.x & 7;
    const int nb = blockIdx.x >> 3;
    const int n0 = nb * 64;
    const int kbase = chunk * 768;
    const int nsi = 768 / KST;     // 6 steps

    // staging map: 4 x 16B issues per thread cover 16KB
    int fo[4], nn[4];
    const char* gg[4];
    #pragma unroll
    for (int i = 0; i < 4; ++i) {
        fo[i] = tid * 16 + i * 4096;
        nn[i] = fo[i] >> 8;                       // 0..63
        const int ko = (fo[i] & 255) ^ ((nn[i] & 7) << 4);
        gg[i] = (const char*)(RT + (size_t)(n0 + nn[i]) * LDK + kbase) + ko;
    }

    size_t arow0 = (size_t)(w * 32 + ln) * LDA + kbase + lg * 8;
    size_t arow1 = arow0 + (size_t)16 * LDA;

    f32x4 acc[2][4];
    #pragma unroll
    for (int a = 0; a < 2; ++a)
        #pragma unroll
        for (int b = 0; b < 4; ++b) {
            acc[a][b][0] = 0.f; acc[a][b][1] = 0.f;
            acc[a][b][2] = 0.f; acc[a][b][3] = 0.f;
        }

    #pragma unroll
    for (int i = 0; i < 4; ++i) gld16(gg[i], &Bs[0][fo[i]]);
    __syncthreads();

    const int swn = (ln & 7) << 4;
    #pragma unroll 1
    for (int t = 0; t < nsi; ++t) {
        if (t + 1 < nsi) {
            const int nb2 = (t + 1) & 1;
            #pragma unroll
            for (int i = 0; i < 4; ++i) gld16(gg[i] + (t + 1) * 256, &Bs[nb2][fo[i]]);
        }
        const unsigned char* buf = Bs[t & 1];
        bf16x8 afr[2][4];
        #pragma unroll
        for (int ks = 0; ks < 4; ++ks) {
            afr[0][ks] = *(const bf16x8*)(A + arow0 + ks * 32);
            afr[1][ks] = *(const bf16x8*)(A + arow1 + ks * 32);
        }
        #pragma unroll
        for (int nt = 0; nt < 4; ++nt) {
            const int rowb = (nt * 16 + ln) * 256;
            #pragma unroll
            for (int ks = 0; ks < 4; ++ks) {
                bf16x8 bfr = *(const bf16x8*)(buf + rowb + (((lg * 16) + ks * 64) ^ swn));
                acc[0][nt] = __builtin_amdgcn_mfma_f32_16x16x32_bf16(afr[0][ks], bfr, acc[0][nt], 0, 0, 0);
                acc[1][nt] = __builtin_amdgcn_mfma_f32_16x16x32_bf16(afr[1][ks], bfr, acc[1][nt], 0, 0, 0);
            }
        }
        arow0 += KST; arow1 += KST;
        __syncthreads();
    }

    float* dst = wpart + (size_t)chunk * PARTF;
    #pragma unroll
    for (int mt = 0; mt < 2; ++mt) {
        const int mbase = w * 32 + mt * 16 + lg * 4;
        #pragma unroll
        for (int nt = 0; nt < 4; ++nt) {
            const size_t cb = (size_t)(n0 + nt * 16 + ln);
            #pragma unroll
            for (int j = 0; j < 4; ++j)
                dst[(size_t)(mbase + j) * LDP + cb] = acc[mt][nt][j];
        }
    }
}

// ---- reduce: out[:, :6144] = clip(sum of 8 slots), out[:, 6144:] = 0 ----
__global__ __launch_bounds__(256) void reduce_kernel(float* __restrict__ out,
        const float* __restrict__ wpart) {
    int q = blockIdx.x * 256 + threadIdx.x;   // 0 .. 196607
    int m = q / (NV / 4);
    int r = q % (NV / 4);
    f32x4 a;
    a[0] = 0.f; a[1] = 0.f; a[2] = 0.f; a[3] = 0.f;
    #pragma unroll 1
    for (int p = 0; p < 8; ++p) {
        f32x4 c = *(const f32x4*)(wpart + (size_t)p * PARTF + (size_t)m * LDP + r * 4);
        #pragma unroll
        for (int i = 0; i < 4; ++i) a[i] += c[i];
    }
    f32x4 cz, z;
    #pragma unroll
    for (int i = 0; i < 4; ++i) {
        cz[i] = fminf(fmaxf(a[i], 0.f), 1.f);
        z[i] = 0.f;
    }
    size_t base = (size_t)m * NPIX + r * 4;
    *(f32x4*)(out + base) = cz;
    *(f32x4*)(out + base + NV) = z;
}

// ================= fallback (ws too small): proven R1 path =================
typedef float2 fl2;
__device__ __forceinline__ bf16x8 cvt8(f32x4 a, f32x4 b) {
    union { unsigned u[4]; bf16x8 v; } r;
    r.u[0] = pk2(a[0], a[1]); r.u[1] = pk2(a[2], a[3]);
    r.u[2] = pk2(b[0], b[1]); r.u[3] = pk2(b[2], b[3]);
    return r.v;
}
__device__ __forceinline__ void sload(const float*& bptr, fl2 (&r)[8]) {
    #pragma unroll
    for (int gi = 0; gi < 4; ++gi) {
        const float* p = bptr + (size_t)(gi * 32) * NV;
        r[2 * gi]     = *(const fl2*)(p);
        r[2 * gi + 1] = *(const fl2*)(p + NV);
    }
    bptr += (size_t)KST * NV;
}
__device__ __forceinline__ void wstage(unsigned char* buf, const fl2 (&r)[8],
                                       int kq, int nq, int sw0, int sw1) {
    #pragma unroll
    for (int gi = 0; gi < 4; ++gi) {
        unsigned lo = pk2(r[2 * gi].x, r[2 * gi + 1].x);
        unsigned hi = pk2(r[2 * gi].y, r[2 * gi + 1].y);
        const int kbyte = (kq + gi * 32) * 2;
        *(unsigned*)(buf + nq * 256       + (kbyte ^ sw0)) = lo;
        *(unsigned*)(buf + (nq + 1) * 256 + (kbyte ^ sw1)) = hi;
    }
}
__device__ __forceinline__ void compute_fb(const unsigned char* buf,
        const float* __restrict__ X, size_t arow0, size_t arow1,
        int ln, int lg, f32x4 (&acc)[2][2]) {
    bf16x8 afr[2][4];
    #pragma unroll
    for (int ks = 0; ks < 4; ++ks) {
        f32x4 p0 = *(const f32x4*)(X + arow0 + ks * 32);
        f32x4 p1 = *(const f32x4*)(X + arow0 + ks * 32 + 4);
        afr[0][ks] = cvt8(p0, p1);
        f32x4 q0 = *(const f32x4*)(X + arow1 + ks * 32);
        f32x4 q1 = *(const f32x4*)(X + arow1 + ks * 32 + 4);
        afr[1][ks] = cvt8(q0, q1);
    }
    const int swn = (ln & 7) << 4;
    #pragma unroll
    for (int nt = 0; nt < 2; ++nt) {
        const int rowb = (nt * 16 + ln) * 256;
        #pragma unroll
        for (int ks = 0; ks < 4; ++ks) {
            bf16x8 bfr = *(const bf16x8*)(buf + rowb + (((lg * 16) + ks * 64) ^ swn));
            acc[0][nt] = __builtin_amdgcn_mfma_f32_16x16x32_bf16(afr[0][ks], bfr, acc[0][nt], 0, 0, 0);
            acc[1][nt] = __builtin_amdgcn_mfma_f32_16x16x32_bf16(afr[1][ks], bfr, acc[1][nt], 0, 0, 0);
        }
    }
}
__global__ __launch_bounds__(256) void gemm_fb_kernel(const float* __restrict__ X,
        const float* __restrict__ R, float* __restrict__ out) {
    __shared__ unsigned char Bs0[32 * 256];
    __shared__ unsigned char Bs1[32 * 256];
    const int tid = threadIdx.x;
    const int w = tid >> 6, l = tid & 63;
    const int ln = l & 15, lg = l >> 4;
    const int chunk = blockIdx.x / 192;
    const int nb = blockIdx.x % 192;
    const int n0 = nb * 32;
    const int kbase = chunk * (NV / 2);
    const int nsi = (NV / 2) / KST;
    const int kq = (tid >> 4) * 2;
    const int nq = (tid & 15) * 2;
    const float* bptr = R + (size_t)(kbase + kq) * NV + (n0 + nq);
    const int sw0 = (nq & 7) << 4;
    const int sw1 = ((nq + 1) & 7) << 4;
    size_t arow0 = (size_t)(w * 32 + ln) * NPIX + kbase + lg * 8;
    size_t arow1 = arow0 + (size_t)16 * NPIX;
    f32x4 acc[2][2];
    #pragma unroll
    for (int a = 0; a < 2; ++a)
        #pragma unroll
        for (int b = 0; b < 2; ++b) {
            acc[a][b][0] = 0.f; acc[a][b][1] = 0.f;
            acc[a][b][2] = 0.f; acc[a][b][3] = 0.f;
        }
    fl2 ring0[8], ring1[8];
    sload(bptr, ring0);
    sload(bptr, ring1);
    wstage(Bs0, ring0, kq, nq, sw0, sw1);
    __syncthreads();
    #pragma unroll 1
    for (int it = 0; it < nsi / 2; ++it) {
        const int s = it * 2;
        if (s + 2 < nsi) sload(bptr, ring0);
        compute_fb(Bs0, X, arow0, arow1, ln, lg, acc);
        arow0 += KST; arow1 += KST;
        wstage(Bs1, ring1, kq, nq, sw0, sw1);
        __syncthreads();
        if (s + 3 < nsi) sload(bptr, ring1);
        compute_fb(Bs1, X, arow0, arow1, ln, lg, acc);
        arow0 += KST; arow1 += KST;
        if (s + 2 < nsi) wstage(Bs0, ring0, kq, nq, sw0, sw1);
        __syncthreads();
    }
    float* dst = out + (size_t)chunk * NV;
    #pragma unroll
    for (int mt = 0; mt < 2; ++mt) {
        const int mbase = w * 32 + mt * 16 + lg * 4;
        #pragma unroll
        for (int nt = 0; nt < 2; ++nt) {
            const size_t cb = (size_t)(n0 + nt * 16 + ln);
            #pragma unroll
            for (int j = 0; j < 4; ++j)
                dst[(size_t)(mbase + j) * NPIX + cb] = acc[mt][nt][j];
        }
    }
}
__global__ __launch_bounds__(256) void reduce_fb_kernel(float* __restrict__ out) {
    int q = blockIdx.x * 256 + threadIdx.x;
    int m = q / (NV / 4);
    int r = q % (NV / 4);
    size_t base = (size_t)m * NPIX + r * 4;
    f32x4 a = *(f32x4*)(out + base);
    f32x4 b = *(f32x4*)(out + base + NV);
    f32x4 cz, z;
    #pragma unroll
    for (int i = 0; i < 4; ++i) {
        float v = a[i] + b[i];
        cz[i] = fminf(fmaxf(v, 0.f), 1.f);
        z[i] = 0.f;
    }
    *(f32x4*)(out + base) = cz;
    *(f32x4*)(out + base + NV) = z;
}

extern "C" void kernel_launch(void* const* d_in, const int* in_sizes, int n_in,
                              void* d_out, int out_size, void* d_ws, size_t ws_size,
                              hipStream_t stream) {
    const float* x = (const float*)d_in[0];   // (8,16,12288) fp32
    const float* R = (const float*)d_in[1];   // (6144,6144) fp32
    float* out = (float*)d_out;               // (8,16,12288) fp32

    const size_t abytes  = (size_t)MR * LDA * 2;       // 1.59 MB
    const size_t rtbytes = (size_t)NV * LDK * 2;       // 76.3 MB
    const size_t wbytes  = 8 * PARTF * 4;              // 25.4 MB

    if (ws_size >= abytes + rtbytes + wbytes) {
        unsigned short* abf = (unsigned short*)d_ws;
        unsigned short* rt  = (unsigned short*)((char*)d_ws + abytes);
        float* wpart = (float*)((char*)d_ws + abytes + rtbytes);
        prep_kernel<<<(MR * NV / 8) / 256, 256, 0, stream>>>(x, abf);
        trans_kernel<<<192 * 24, 256, 0, stream>>>(R, rt);
        gemm2_kernel<<<96 * 8, 256, 0, stream>>>(abf, rt, wpart);
        reduce_kernel<<<(MR * NV / 4) / 256, 256, 0, stream>>>(out, wpart);
    } else {
        gemm_fb_kernel<<<192 * 2, 256, 0, stream>>>(x, R, out);
        reduce_fb_kernel<<<(MR * NV / 4) / 256, 256, 0, stream>>>(out);
    }
}

// Round 6
// 236.300 us; speedup vs baseline: 1.2394x; 1.2394x over previous
//
#include <hip/hip_runtime.h>
#include <hip/hip_bf16.h>

// out[128,12288] = [ clip(x[:, :6144] @ R, 0, 1) | zeros ]
// M=128, K=N=6144. R (151 MB fp32) streamed ONCE, fused transpose-in-registers:
// gemm3 reads R[k][n] natural layout in 256B segments, k-transposes 8x4 blocks
// in regs (pk2 -> bf16), ds_write_b128 into swizzled [n][k] LDS, MFMA 16x16x32.
// K split 8 ways (chunk = bid&7 -> XCD-exclusive R slice + shared A slice in L2).
// fp32 partials (padded pitch) -> reduce (+clip, zero tail).

#define NPIX 12288
#define NV   6144
#define MR   128
#define KST  128
#define LDA  6208   // A row pitch (shorts)
#define LDP  6208   // partial-slot row pitch (floats)
#define PARTF ((size_t)MR * LDP)

typedef __attribute__((ext_vector_type(8))) short bf16x8;
typedef __attribute__((ext_vector_type(4))) float f32x4;
typedef __attribute__((ext_vector_type(4))) unsigned u32x4;

__device__ __forceinline__ unsigned pk2(float lo, float hi) {
    __hip_bfloat162 h = __float22bfloat162_rn(make_float2(lo, hi));
    union { __hip_bfloat162 h; unsigned u; } v; v.h = h; return v.u;
}

// ---- prep: x[:, :6144] fp32 -> bf16 A[128][LDA] ----
__global__ __launch_bounds__(256) void prep_kernel(const float* __restrict__ x,
                                                   unsigned short* __restrict__ abf) {
    int q = blockIdx.x * 256 + threadIdx.x;   // 0 .. 98303
    int m = q / (NV / 8);
    int r = q % (NV / 8);
    int k = r * 8;
    const float* src = x + (size_t)m * NPIX + k;
    f32x4 a = *(const f32x4*)(src);
    f32x4 b = *(const f32x4*)(src + 4);
    u32x4 o;
    o[0] = pk2(a[0], a[1]); o[1] = pk2(a[2], a[3]);
    o[2] = pk2(b[0], b[1]); o[3] = pk2(b[2], b[3]);
    *(u32x4*)(abf + (size_t)m * LDA + k) = o;
}

// ---- gemm3 staging: read 8 k-rows x 16B (4 n) per thread, 256B segments ----
__device__ __forceinline__ void sload3(const float*& rp, f32x4 (&r)[8]) {
    #pragma unroll
    for (int j = 0; j < 8; ++j) r[j] = *(const f32x4*)(rp + (size_t)j * NV);
    rp += (size_t)KST * NV;
}

// register k-transpose + bf16 pack + swizzled LDS write (4 x ds_write_b128)
__device__ __forceinline__ void wstage3(unsigned char* buf, const f32x4 (&r)[8],
                                        int q, int kb) {
    #pragma unroll
    for (int c = 0; c < 4; ++c) {
        const int n_loc = q * 4 + c;
        u32x4 o;
        o[0] = pk2(r[0][c], r[1][c]);
        o[1] = pk2(r[2][c], r[3][c]);
        o[2] = pk2(r[4][c], r[5][c]);
        o[3] = pk2(r[6][c], r[7][c]);
        *(u32x4*)(buf + n_loc * 256 + (kb ^ ((n_loc & 7) << 4))) = o;
    }
}

__device__ __forceinline__ void compute3(const unsigned char* buf,
        const unsigned short* __restrict__ A,
        size_t arow0, size_t arow1, int ln, int lg, f32x4 (&acc)[2][4]) {
    bf16x8 afr[2][4];
    #pragma unroll
    for (int ks = 0; ks < 4; ++ks) {
        afr[0][ks] = *(const bf16x8*)(A + arow0 + ks * 32);
        afr[1][ks] = *(const bf16x8*)(A + arow1 + ks * 32);
    }
    const int swn = (ln & 7) << 4;
    #pragma unroll
    for (int nt = 0; nt < 4; ++nt) {
        const int rowb = (nt * 16 + ln) * 256;
        #pragma unroll
        for (int ks = 0; ks < 4; ++ks) {
            bf16x8 bfr = *(const bf16x8*)(buf + rowb + (((lg * 16) + ks * 64) ^ swn));
            acc[0][nt] = __builtin_amdgcn_mfma_f32_16x16x32_bf16(afr[0][ks], bfr, acc[0][nt], 0, 0, 0);
            acc[1][nt] = __builtin_amdgcn_mfma_f32_16x16x32_bf16(afr[1][ks], bfr, acc[1][nt], 0, 0, 0);
        }
    }
}

// ---- gemm3: A[128][LDA]bf16 x R[k][n]fp32 (fused transpose) -> 8 partials ----
// grid 768 = 96 n-stripes x 8 k-chunks (chunk = bid&7, XCD-aligned).
// Per step: [128 k][64 n] fp32 tile; wave w covers k-rows w*32..w*32+31.
__global__ __launch_bounds__(256) void gemm3_kernel(
        const unsigned short* __restrict__ A,
        const float* __restrict__ R,
        float* __restrict__ wpart) {
    __shared__ __align__(64) unsigned char Bs0[16384];  // [64 n][256 B k], swizzled
    __shared__ __align__(64) unsigned char Bs1[16384];

    const int tid = threadIdx.x;
    const int w = tid >> 6, l = tid & 63;
    const int ln = l & 15, lg = l >> 4;     // lg doubles as k-octet in staging
    const int q = ln;                        // n-chunk (16B) in staging
    const int chunk = blockIdx.x & 7;
    const int nb = blockIdx.x >> 3;
    const int n0 = nb * 64;
    const int kbase = chunk * 768;
    const int nsi = 768 / KST;               // 6 steps
    const int kb = w * 64 + lg * 16;         // this thread's k-octet byte offset

    const float* rp = R + (size_t)(kbase + w * 32 + lg * 8) * NV + n0 + q * 4;

    size_t arow0 = (size_t)(w * 32 + ln) * LDA + kbase + lg * 8;
    size_t arow1 = arow0 + (size_t)16 * LDA;

    f32x4 acc[2][4];
    #pragma unroll
    for (int a = 0; a < 2; ++a)
        #pragma unroll
        for (int b = 0; b < 4; ++b) {
            acc[a][b][0] = 0.f; acc[a][b][1] = 0.f;
            acc[a][b][2] = 0.f; acc[a][b][3] = 0.f;
        }

    f32x4 ring0[8], ring1[8];
    sload3(rp, ring0);                 // step 0
    sload3(rp, ring1);                 // step 1
    wstage3(Bs0, ring0, q, kb);        // stage step 0
    __syncthreads();

    #pragma unroll 1
    for (int it = 0; it < nsi / 2; ++it) {
        const int s = it * 2;
        if (s + 2 < nsi) sload3(rp, ring0);            // prefetch step s+2
        compute3(Bs0, A, arow0, arow1, ln, lg, acc);   // compute step s
        arow0 += KST; arow1 += KST;
        wstage3(Bs1, ring1, q, kb);                    // stage step s+1
        __syncthreads();
        if (s + 3 < nsi) sload3(rp, ring1);            // prefetch step s+3
        compute3(Bs1, A, arow0, arow1, ln, lg, acc);   // compute step s+1
        arow0 += KST; arow1 += KST;
        if (s + 2 < nsi) wstage3(Bs0, ring0, q, kb);   // stage step s+2
        __syncthreads();
    }

    float* dst = wpart + (size_t)chunk * PARTF;
    #pragma unroll
    for (int mt = 0; mt < 2; ++mt) {
        const int mbase = w * 32 + mt * 16 + lg * 4;
        #pragma unroll
        for (int nt = 0; nt < 4; ++nt) {
            const size_t cb = (size_t)(n0 + nt * 16 + ln);
            #pragma unroll
            for (int j = 0; j < 4; ++j)
                dst[(size_t)(mbase + j) * LDP + cb] = acc[mt][nt][j];
        }
    }
}

// ---- reduce: out[:, :6144] = clip(sum of 8 slots), out[:, 6144:] = 0 ----
__global__ __launch_bounds__(256) void reduce_kernel(float* __restrict__ out,
        const float* __restrict__ wpart) {
    int q = blockIdx.x * 256 + threadIdx.x;   // 0 .. 196607
    int m = q / (NV / 4);
    int r = q % (NV / 4);
    f32x4 a;
    a[0] = 0.f; a[1] = 0.f; a[2] = 0.f; a[3] = 0.f;
    #pragma unroll 1
    for (int p = 0; p < 8; ++p) {
        f32x4 c = *(const f32x4*)(wpart + (size_t)p * PARTF + (size_t)m * LDP + r * 4);
        #pragma unroll
        for (int i = 0; i < 4; ++i) a[i] += c[i];
    }
    f32x4 cz, z;
    #pragma unroll
    for (int i = 0; i < 4; ++i) {
        cz[i] = fminf(fmaxf(a[i], 0.f), 1.f);
        z[i] = 0.f;
    }
    size_t base = (size_t)m * NPIX + r * 4;
    *(f32x4*)(out + base) = cz;
    *(f32x4*)(out + base + NV) = z;
}

// ================= fallback (ws too small): proven R1 path =================
typedef float2 fl2;
__device__ __forceinline__ bf16x8 cvt8(f32x4 a, f32x4 b) {
    union { unsigned u[4]; bf16x8 v; } r;
    r.u[0] = pk2(a[0], a[1]); r.u[1] = pk2(a[2], a[3]);
    r.u[2] = pk2(b[0], b[1]); r.u[3] = pk2(b[2], b[3]);
    return r.v;
}
__device__ __forceinline__ void sload(const float*& bptr, fl2 (&r)[8]) {
    #pragma unroll
    for (int gi = 0; gi < 4; ++gi) {
        const float* p = bptr + (size_t)(gi * 32) * NV;
        r[2 * gi]     = *(const fl2*)(p);
        r[2 * gi + 1] = *(const fl2*)(p + NV);
    }
    bptr += (size_t)KST * NV;
}
__device__ __forceinline__ void wstage(unsigned char* buf, const fl2 (&r)[8],
                                       int kq, int nq, int sw0, int sw1) {
    #pragma unroll
    for (int gi = 0; gi < 4; ++gi) {
        unsigned lo = pk2(r[2 * gi].x, r[2 * gi + 1].x);
        unsigned hi = pk2(r[2 * gi].y, r[2 * gi + 1].y);
        const int kbyte = (kq + gi * 32) * 2;
        *(unsigned*)(buf + nq * 256       + (kbyte ^ sw0)) = lo;
        *(unsigned*)(buf + (nq + 1) * 256 + (kbyte ^ sw1)) = hi;
    }
}
__device__ __forceinline__ void compute_fb(const unsigned char* buf,
        const float* __restrict__ X, size_t arow0, size_t arow1,
        int ln, int lg, f32x4 (&acc)[2][2]) {
    bf16x8 afr[2][4];
    #pragma unroll
    for (int ks = 0; ks < 4; ++ks) {
        f32x4 p0 = *(const f32x4*)(X + arow0 + ks * 32);
        f32x4 p1 = *(const f32x4*)(X + arow0 + ks * 32 + 4);
        afr[0][ks] = cvt8(p0, p1);
        f32x4 q0 = *(const f32x4*)(X + arow1 + ks * 32);
        f32x4 q1 = *(const f32x4*)(X + arow1 + ks * 32 + 4);
        afr[1][ks] = cvt8(q0, q1);
    }
    const int swn = (ln & 7) << 4;
    #pragma unroll
    for (int nt = 0; nt < 2; ++nt) {
        const int rowb = (nt * 16 + ln) * 256;
        #pragma unroll
        for (int ks = 0; ks < 4; ++ks) {
            bf16x8 bfr = *(const bf16x8*)(buf + rowb + (((lg * 16) + ks * 64) ^ swn));
            acc[0][nt] = __builtin_amdgcn_mfma_f32_16x16x32_bf16(afr[0][ks], bfr, acc[0][nt], 0, 0, 0);
            acc[1][nt] = __builtin_amdgcn_mfma_f32_16x16x32_bf16(afr[1][ks], bfr, acc[1][nt], 0, 0, 0);
        }
    }
}
__global__ __launch_bounds__(256) void gemm_fb_kernel(const float* __restrict__ X,
        const float* __restrict__ R, float* __restrict__ out) {
    __shared__ unsigned char Bs0[32 * 256];
    __shared__ unsigned char Bs1[32 * 256];
    const int tid = threadIdx.x;
    const int w = tid >> 6, l = tid & 63;
    const int ln = l & 15, lg = l >> 4;
    const int chunk = blockIdx.x / 192;
    const int nb = blockIdx.x % 192;
    const int n0 = nb * 32;
    const int kbase = chunk * (NV / 2);
    const int nsi = (NV / 2) / KST;
    const int kq = (tid >> 4) * 2;
    const int nq = (tid & 15) * 2;
    const float* bptr = R + (size_t)(kbase + kq) * NV + (n0 + nq);
    const int sw0 = (nq & 7) << 4;
    const int sw1 = ((nq + 1) & 7) << 4;
    size_t arow0 = (size_t)(w * 32 + ln) * NPIX + kbase + lg * 8;
    size_t arow1 = arow0 + (size_t)16 * NPIX;
    f32x4 acc[2][2];
    #pragma unroll
    for (int a = 0; a < 2; ++a)
        #pragma unroll
        for (int b = 0; b < 2; ++b) {
            acc[a][b][0] = 0.f; acc[a][b][1] = 0.f;
            acc[a][b][2] = 0.f; acc[a][b][3] = 0.f;
        }
    fl2 ring0[8], ring1[8];
    sload(bptr, ring0);
    sload(bptr, ring1);
    wstage(Bs0, ring0, kq, nq, sw0, sw1);
    __syncthreads();
    #pragma unroll 1
    for (int it = 0; it < nsi / 2; ++it) {
        const int s = it * 2;
        if (s + 2 < nsi) sload(bptr, ring0);
        compute_fb(Bs0, X, arow0, arow1, ln, lg, acc);
        arow0 += KST; arow1 += KST;
        wstage(Bs1, ring1, kq, nq, sw0, sw1);
        __syncthreads();
        if (s + 3 < nsi) sload(bptr, ring1);
        compute_fb(Bs1, X, arow0, arow1, ln, lg, acc);
        arow0 += KST; arow1 += KST;
        if (s + 2 < nsi) wstage(Bs0, ring0, kq, nq, sw0, sw1);
        __syncthreads();
    }
    float* dst = out + (size_t)chunk * NV;
    #pragma unroll
    for (int mt = 0; mt < 2; ++mt) {
        const int mbase = w * 32 + mt * 16 + lg * 4;
        #pragma unroll
        for (int nt = 0; nt < 2; ++nt) {
            const size_t cb = (size_t)(n0 + nt * 16 + ln);
            #pragma unroll
            for (int j = 0; j < 4; ++j)
                dst[(size_t)(mbase + j) * NPIX + cb] = acc[mt][nt][j];
        }
    }
}
__global__ __launch_bounds__(256) void reduce_fb_kernel(float* __restrict__ out) {
    int q = blockIdx.x * 256 + threadIdx.x;
    int m = q / (NV / 4);
    int r = q % (NV / 4);
    size_t base = (size_t)m * NPIX + r * 4;
    f32x4 a = *(f32x4*)(out + base);
    f32x4 b = *(f32x4*)(out + base + NV);
    f32x4 cz, z;
    #pragma unroll
    for (int i = 0; i < 4; ++i) {
        float v = a[i] + b[i];
        cz[i] = fminf(fmaxf(v, 0.f), 1.f);
        z[i] = 0.f;
    }
    *(f32x4*)(out + base) = cz;
    *(f32x4*)(out + base + NV) = z;
}

extern "C" void kernel_launch(void* const* d_in, const int* in_sizes, int n_in,
                              void* d_out, int out_size, void* d_ws, size_t ws_size,
                              hipStream_t stream) {
    const float* x = (const float*)d_in[0];   // (8,16,12288) fp32
    const float* R = (const float*)d_in[1];   // (6144,6144) fp32
    float* out = (float*)d_out;               // (8,16,12288) fp32

    const size_t abytes = (size_t)MR * LDA * 2;   // 1.59 MB bf16 A
    const size_t wbytes = 8 * PARTF * 4;          // 25.4 MB partial slots

    if (ws_size >= abytes + wbytes) {
        unsigned short* abf = (unsigned short*)d_ws;
        float* wpart = (float*)((char*)d_ws + abytes);
        prep_kernel<<<(MR * NV / 8) / 256, 256, 0, stream>>>(x, abf);
        gemm3_kernel<<<96 * 8, 256, 0, stream>>>(abf, R, wpart);
        reduce_kernel<<<(MR * NV / 4) / 256, 256, 0, stream>>>(out, wpart);
    } else {
        gemm_fb_kernel<<<192 * 2, 256, 0, stream>>>(x, R, out);
        reduce_fb_kernel<<<(MR * NV / 4) / 256, 256, 0, stream>>>(out);
    }
}